// Round 1
// 274.357 us; speedup vs baseline: 1.0520x; 1.0520x over previous
//
#include <hip/hip_runtime.h>
#include <hip/hip_bf16.h>
#include <stdint.h>

#define TLEN 480
#define NB 128
#define NC 256

typedef short bf16x8 __attribute__((ext_vector_type(8)));
typedef float f32x4 __attribute__((ext_vector_type(4)));
typedef unsigned short u16;
typedef unsigned int u32;

__device__ inline u16 f2bf(float f) {   // RNE, used for the A operator (built once)
    union { float f; uint32_t u; } v; v.f = f;
    uint32_t u = v.u;
    return (u16)((u + 0x7fffu + ((u >> 16) & 1u)) >> 16);
}

// pack two fp32 -> (bf16(hi)<<16)|bf16(lo) by truncation: one v_perm_b32
__device__ inline u32 pack2bf(float lo, float hi) {
    return __builtin_amdgcn_perm(__float_as_uint(hi), __float_as_uint(lo), 0x07060302u);
}

// degree-1 LOESS weights, compact: fills w[0..q-1] for columns [left, left+q-1], returns left.
__device__ int loess_w(int t, int n, int q, float* out) {
    int left = t - (q - 1) / 2;
    if (left < 0) left = 0;
    if (left > n - q) left = n - q;
    int right = left + q - 1;
    int h = (t - left) > (right - t) ? (t - left) : (right - t);
    double w[29];
    double wsum = 0.0;
    for (int i = 0; i < q; ++i) {
        double dist = fabs((double)(left + i - t)) / (double)h;
        double u = 1.0 - dist * dist * dist;
        if (u < 0.0) u = 0.0;
        double wv = u * u * u;
        w[i] = wv; wsum += wv;
    }
    for (int i = 0; i < q; ++i) w[i] /= wsum;
    double xbar = 0.0;
    for (int i = 0; i < q; ++i) xbar += w[i] * (double)(left + i);
    double var = 0.0;
    for (int i = 0; i < q; ++i) { double d = (double)(left + i) - xbar; var += w[i] * d * d; }
    if (var > 1e-12) {
        double tb = (double)t - xbar;
        for (int i = 0; i < q; ++i) {
            double d = (double)(left + i) - xbar;
            out[i] = (float)(w[i] * (1.0 + tb * d / var));
        }
    } else {
        for (int i = 0; i < q; ++i) out[i] = (float)w[i];
    }
    return left;
}

// Ms dense (34x32), MlpC (480x17 compact), MtC (480x29 compact), w3 (31-tap MA15*MA15*MA3)
// w3 parallelized across 31 threads (was a single-thread 1395-iteration fp64 loop).
__global__ void k_loess(float* Ms, float* w3, float* MlpC, float* MtC) {
    int gid = blockIdx.x * 256 + threadIdx.x;
    if (gid < 34) {
        float wl[7];
        int left = loess_w(gid - 1, 32, 7, wl);
        float* row = Ms + gid * 32;
        #pragma unroll
        for (int i = 0; i < 32; ++i) row[i] = 0.0f;
        for (int i = 0; i < 7; ++i) row[left + i] = wl[i];
    } else if (gid < 514) {
        int t = gid - 34;
        float wl[17];
        loess_w(t, TLEN, 17, wl);
        for (int i = 0; i < 17; ++i) MlpC[t * 17 + i] = wl[i];
    } else if (gid < 994) {
        int t = gid - 514;
        float wl[29];
        loess_w(t, TLEN, 29, wl);
        for (int i = 0; i < 29; ++i) MtC[t * 29 + i] = wl[i];
    } else if (gid < 1025) {
        int d = gid - 994;            // 0..30
        int cnt = 0;
        for (int c = 0; c < 3; ++c)
            for (int a = 0; a < 15; ++a) {
                int b = d - a - c;
                if (b >= 0 && b < 15) cnt++;
            }
        w3[d] = (float)((double)cnt / 675.0);
    }
}

// S[t][u] = Ecenter[t][u] - sum_{k<17} MlpC[t][k] * G[slp(t)+k][u]
__global__ void k_S(const float* __restrict__ Ms, const float* __restrict__ w3,
                    const float* __restrict__ MlpC, float* __restrict__ S) {
    int id = blockIdx.x * 256 + threadIdx.x;
    if (id >= TLEN * TLEN) return;
    int t = id / TLEN, u = id - t * TLEN;
    int nu = u / 15, ju = u - nu * 15;
    int slp = t - 8;
    if (slp < 0) slp = 0;
    if (slp > TLEN - 17) slp = TLEN - 17;
    float acc = 0.0f;
    for (int k = 0; k < 17; ++k) {
        int i = slp + k;
        int s_lo = (i - ju + 14) / 15;
        float g = 0.0f;
        #pragma unroll
        for (int ds = 0; ds < 3; ++ds) {
            int s = s_lo + ds;
            int d = s * 15 + ju - i;
            if (s >= 0 && s < 34 && d >= 0 && d <= 30)
                g += Ms[s * 32 + nu] * w3[d];
        }
        acc += MlpC[t * 17 + k] * g;
    }
    float val = -acc;
    if (t % 15 == ju) val += Ms[(1 + t / 15) * 32 + nu];
    S[id] = val;
}

// V = Mt @ S (banded 29), U = Mt - V (Mt from compact)
__global__ void k_VU(const float* __restrict__ MtC, const float* __restrict__ S,
                     float* __restrict__ U, float* __restrict__ V) {
    int id = blockIdx.x * 256 + threadIdx.x;
    if (id >= TLEN * TLEN) return;
    int t = id / TLEN, u = id - t * TLEN;
    int st = t - 14;
    if (st < 0) st = 0;
    if (st > TLEN - 29) st = TLEN - 29;
    float acc = 0.0f;
    for (int k = 0; k < 29; ++k)
        acc += MtC[t * 29 + k] * S[(size_t)(st + k) * TLEN + u];
    float mt = (u >= st && u < st + 29) ? MtC[t * 29 + (u - st)] : 0.0f;
    V[id] = acc;
    U[id] = mt - acc;
}

// A = U + V@U, output bf16 (RNE); 16x16 LDS-tiled fp32 matmul (480^3, tiny)
__global__ void k_A(const float* __restrict__ U, const float* __restrict__ V,
                    u16* __restrict__ Abf) {
    __shared__ float Vs[16][17];
    __shared__ float Us[16][17];
    int tx = threadIdx.x, ty = threadIdx.y;
    int u = blockIdx.x * 16 + tx;
    int t = blockIdx.y * 16 + ty;
    float acc = 0.0f;
    for (int kt = 0; kt < 30; ++kt) {
        Vs[ty][tx] = V[(size_t)t * TLEN + kt * 16 + tx];
        Us[ty][tx] = U[(size_t)(kt * 16 + ty) * TLEN + u];
        __syncthreads();
        #pragma unroll
        for (int e = 0; e < 16; ++e) acc += Vs[ty][e] * Us[e][tx];
        __syncthreads();
    }
    Abf[(size_t)t * TLEN + u] = f2bf(U[(size_t)t * TLEN + u] + acc);
}

// Fused transpose+GEMM: trend = A @ x_b^T per batch; out1 = trend, out0 = x - trend.
//
// v2 (pipelined): grid (b, 5 t-tiles of 96, 2 c-halves of 128).  Per k-step a block
// stages x[b, k0:k0+32, chalf] -> LDS bf16 [c][k] (stride 40 u16, k-group XOR swizzle,
// identical scheme to v1).  Changes vs v1:
//   - DOUBLE-BUFFERED LDS (2 x 10 KB) -> ONE barrier per k-step (was 2).
//   - Register prefetch: the 4 float4 loads for step s+1 are ISSUED before the barrier
//     of step s and consumed (packed) after it -> global-load latency hides under the
//     ds_read+MFMA phase; loads stay in flight across the barrier.
//   - Per-wave output tile is 32c x 96t: epilogue writes full 128B lines in adjacent
//     nontemporal stores (v1 wrote complementary 64B half-lines ~6 stores apart ->
//     1.3x HBM write amplification).
// Batch on blockIdx.x => all 10 blocks of batch b on XCD b%8 as before.
__global__ __launch_bounds__(256, 4)
void k_gemm(const u16* __restrict__ A, const float* __restrict__ x,
            float* __restrict__ out0, float* __restrict__ out1) {
    __shared__ u16 Xs[2][128 * 40];
    int b = blockIdx.x;
    int t0 = blockIdx.y * 96;
    int cz = blockIdx.z * 128;           // global c offset of this block's half
    int tid = threadIdx.x;
    int wave = tid >> 6, lane = tid & 63;
    int lane15 = lane & 15, quad = lane >> 4;
    int cw = wave * 32;                  // LDS-local c base of this wave

    // staging role: thread handles k-quad kkq (4 rows) x one c-quad of the 128-c half
    int kkq = tid >> 5;                  // 0..7
    int wq  = tid & 31;                  // c-quad index within the half
    int kq_sw = kkq ^ ((wq & 3) << 1);   // swizzled k-halfgroup position
    int c0 = wq * 4;                     // LDS-local channel base for staging

    const float* xp0 = x + (size_t)b * TLEN * NC + (size_t)(kkq * 4) * NC + cz + c0;

    // B-operand rows (n = t): A operator rows, bf16, L2-resident
    const u16* bp = A + (size_t)(t0 + lane15) * TLEN + quad * 8;

    f32x4 acc[2][6] = {};

    // prologue: issue loads for step 0
    float4 r[4];
    #pragma unroll
    for (int q = 0; q < 4; ++q) r[q] = *(const float4*)(xp0 + q * NC);

    #pragma unroll
    for (int s = 0; s < 15; ++s) {
        const int pb = s & 1;
        const int k0 = s * 32;

        // pack current regs -> LDS buffer pb (anti-dep: loads below reuse r)
        {
            u32* base32 = (u32*)Xs[pb];
            int o0 = c0 * 20 + kq_sw * 2;    // u32 offset = (c*40 + kq_sw*4)/2
            uint2 w;
            w.x = pack2bf(r[0].x, r[1].x); w.y = pack2bf(r[2].x, r[3].x);
            *(uint2*)(base32 + o0) = w;
            w.x = pack2bf(r[0].y, r[1].y); w.y = pack2bf(r[2].y, r[3].y);
            *(uint2*)(base32 + o0 + 20) = w;
            w.x = pack2bf(r[0].z, r[1].z); w.y = pack2bf(r[2].z, r[3].z);
            *(uint2*)(base32 + o0 + 40) = w;
            w.x = pack2bf(r[0].w, r[1].w); w.y = pack2bf(r[2].w, r[3].w);
            *(uint2*)(base32 + o0 + 60) = w;
        }

        // issue next step's global loads BEFORE the barrier; they complete during
        // this step's ds_read/MFMA phase (and are waited on by next step's pack).
        if (s < 14) {
            const float* xp = xp0 + (size_t)(s + 1) * 32 * NC;
            #pragma unroll
            for (int q = 0; q < 4; ++q) r[q] = *(const float4*)(xp + q * NC);
        }

        __syncthreads();   // single barrier per step (double buffer)

        bf16x8 af[2];
        #pragma unroll
        for (int i = 0; i < 2; ++i) {
            int c = cw + i * 16 + lane15;               // LDS-local
            int qp = quad ^ ((c >> 2) & 3);
            af[i] = *(const bf16x8*)&Xs[pb][c * 40 + qp * 8];
        }
        #pragma unroll
        for (int j = 0; j < 6; ++j) {
            bf16x8 bfr = *(const bf16x8*)(bp + (size_t)j * 16 * TLEN + k0);
            acc[0][j] = __builtin_amdgcn_mfma_f32_16x16x32_bf16(af[0], bfr, acc[0][j], 0, 0, 0);
            acc[1][j] = __builtin_amdgcn_mfma_f32_16x16x32_bf16(af[1], bfr, acc[1][j], 0, 0, 0);
        }
    }

    // D[m=c][n=t]: col(lane15) = t-offset, row(quad*4+r) = c-offset -> f32x4 in c.
    // Per (j, wave): the two i-stores cover one full 128B line, issued back-to-back.
    #pragma unroll
    for (int j = 0; j < 6; ++j) {
        int t = t0 + j * 16 + lane15;
        size_t rowb = ((size_t)b * TLEN + t) * NC + cz + cw + quad * 4;
        f32x4 xv0 = *(const f32x4*)(x + rowb);
        f32x4 xv1 = *(const f32x4*)(x + rowb + 16);
        f32x4 tv0 = acc[0][j];
        f32x4 tv1 = acc[1][j];
        __builtin_nontemporal_store(tv0, (f32x4*)(out1 + rowb));
        __builtin_nontemporal_store(tv1, (f32x4*)(out1 + rowb + 16));
        __builtin_nontemporal_store(xv0 - tv0, (f32x4*)(out0 + rowb));
        __builtin_nontemporal_store(xv1 - tv1, (f32x4*)(out0 + rowb + 16));
    }
}

extern "C" void kernel_launch(void* const* d_in, const int* in_sizes, int n_in,
                              void* d_out, int out_size, void* d_ws, size_t ws_size,
                              hipStream_t stream) {
    const float* x = (const float*)d_in[0];
    float* out0 = (float*)d_out;                           // seasonal + resid = x - trend
    float* out1 = (float*)d_out + (size_t)NB * TLEN * NC;  // trend

    char* ws = (char*)d_ws;
    size_t oMs  = 0;                       // 34*32*4 = 4352
    size_t oW3  = oMs + 4352;              // 128
    size_t oLpC = oW3 + 128;               // 480*17*4 = 32640
    size_t oMtC = oLpC + 32640;            // 480*29*4 = 55680
    size_t oS   = oMtC + 55680;            // 921600
    size_t oU   = oS + 921600;
    size_t oV   = oU + 921600;
    size_t oA   = oV + 921600;             // bf16 460800

    float* Ms   = (float*)(ws + oMs);
    float* w3   = (float*)(ws + oW3);
    float* MlpC = (float*)(ws + oLpC);
    float* MtC  = (float*)(ws + oMtC);
    float* S    = (float*)(ws + oS);
    float* U    = (float*)(ws + oU);
    float* V    = (float*)(ws + oV);
    u16*   Abf  = (u16*)(ws + oA);

    k_loess<<<5, 256, 0, stream>>>(Ms, w3, MlpC, MtC);
    k_S<<<900, 256, 0, stream>>>(Ms, w3, MlpC, S);
    k_VU<<<900, 256, 0, stream>>>(MtC, S, U, V);
    k_A<<<dim3(30, 30), dim3(16, 16), 0, stream>>>(U, V, Abf);
    k_gemm<<<dim3(NB, 5, 2), 256, 0, stream>>>(Abf, x, out0, out1);
}

// Round 2
// 253.988 us; speedup vs baseline: 1.1364x; 1.0802x over previous
//
#include <hip/hip_runtime.h>
#include <hip/hip_bf16.h>
#include <stdint.h>

#define TLEN 480
#define NB 128
#define NC 256

typedef short bf16x8 __attribute__((ext_vector_type(8)));
typedef float f32x4 __attribute__((ext_vector_type(4)));
typedef unsigned short u16;
typedef unsigned int u32;

__device__ inline u16 f2bf(float f) {   // RNE, used for the A operator (built once)
    union { float f; uint32_t u; } v; v.f = f;
    uint32_t u = v.u;
    return (u16)((u + 0x7fffu + ((u >> 16) & 1u)) >> 16);
}

// pack two fp32 -> (bf16(hi)<<16)|bf16(lo) by truncation: one v_perm_b32
__device__ inline u32 pack2bf(float lo, float hi) {
    return __builtin_amdgcn_perm(__float_as_uint(hi), __float_as_uint(lo), 0x07060302u);
}

// degree-1 LOESS weights, compact: fills w[0..q-1] for columns [left, left+q-1], returns left.
__device__ int loess_w(int t, int n, int q, float* out) {
    int left = t - (q - 1) / 2;
    if (left < 0) left = 0;
    if (left > n - q) left = n - q;
    int right = left + q - 1;
    int h = (t - left) > (right - t) ? (t - left) : (right - t);
    double w[29];
    double wsum = 0.0;
    for (int i = 0; i < q; ++i) {
        double dist = fabs((double)(left + i - t)) / (double)h;
        double u = 1.0 - dist * dist * dist;
        if (u < 0.0) u = 0.0;
        double wv = u * u * u;
        w[i] = wv; wsum += wv;
    }
    for (int i = 0; i < q; ++i) w[i] /= wsum;
    double xbar = 0.0;
    for (int i = 0; i < q; ++i) xbar += w[i] * (double)(left + i);
    double var = 0.0;
    for (int i = 0; i < q; ++i) { double d = (double)(left + i) - xbar; var += w[i] * d * d; }
    if (var > 1e-12) {
        double tb = (double)t - xbar;
        for (int i = 0; i < q; ++i) {
            double d = (double)(left + i) - xbar;
            out[i] = (float)(w[i] * (1.0 + tb * d / var));
        }
    } else {
        for (int i = 0; i < q; ++i) out[i] = (float)w[i];
    }
    return left;
}

// Ms dense (34x32), MlpC (480x17 compact), MtC (480x29 compact), w3 (31-tap MA15*MA15*MA3)
__global__ void k_loess(float* Ms, float* w3, float* MlpC, float* MtC) {
    int gid = blockIdx.x * 256 + threadIdx.x;
    if (gid < 34) {
        float wl[7];
        int left = loess_w(gid - 1, 32, 7, wl);
        float* row = Ms + gid * 32;
        #pragma unroll
        for (int i = 0; i < 32; ++i) row[i] = 0.0f;
        for (int i = 0; i < 7; ++i) row[left + i] = wl[i];
    } else if (gid < 514) {
        int t = gid - 34;
        float wl[17];
        loess_w(t, TLEN, 17, wl);
        for (int i = 0; i < 17; ++i) MlpC[t * 17 + i] = wl[i];
    } else if (gid < 994) {
        int t = gid - 514;
        float wl[29];
        loess_w(t, TLEN, 29, wl);
        for (int i = 0; i < 29; ++i) MtC[t * 29 + i] = wl[i];
    } else if (gid < 1025) {
        int d = gid - 994;            // 0..30
        int cnt = 0;
        for (int c = 0; c < 3; ++c)
            for (int a = 0; a < 15; ++a) {
                int b = d - a - c;
                if (b >= 0 && b < 15) cnt++;
            }
        w3[d] = (float)((double)cnt / 675.0);
    }
}

// S[t][u] = Ecenter[t][u] - sum_{k<17} MlpC[t][k] * G[slp(t)+k][u]
__global__ void k_S(const float* __restrict__ Ms, const float* __restrict__ w3,
                    const float* __restrict__ MlpC, float* __restrict__ S) {
    int id = blockIdx.x * 256 + threadIdx.x;
    if (id >= TLEN * TLEN) return;
    int t = id / TLEN, u = id - t * TLEN;
    int nu = u / 15, ju = u - nu * 15;
    int slp = t - 8;
    if (slp < 0) slp = 0;
    if (slp > TLEN - 17) slp = TLEN - 17;
    float acc = 0.0f;
    for (int k = 0; k < 17; ++k) {
        int i = slp + k;
        int s_lo = (i - ju + 14) / 15;
        float g = 0.0f;
        #pragma unroll
        for (int ds = 0; ds < 3; ++ds) {
            int s = s_lo + ds;
            int d = s * 15 + ju - i;
            if (s >= 0 && s < 34 && d >= 0 && d <= 30)
                g += Ms[s * 32 + nu] * w3[d];
        }
        acc += MlpC[t * 17 + k] * g;
    }
    float val = -acc;
    if (t % 15 == ju) val += Ms[(1 + t / 15) * 32 + nu];
    S[id] = val;
}

// V = Mt @ S (banded 29), U = Mt - V (Mt from compact)
__global__ void k_VU(const float* __restrict__ MtC, const float* __restrict__ S,
                     float* __restrict__ U, float* __restrict__ V) {
    int id = blockIdx.x * 256 + threadIdx.x;
    if (id >= TLEN * TLEN) return;
    int t = id / TLEN, u = id - t * TLEN;
    int st = t - 14;
    if (st < 0) st = 0;
    if (st > TLEN - 29) st = TLEN - 29;
    float acc = 0.0f;
    for (int k = 0; k < 29; ++k)
        acc += MtC[t * 29 + k] * S[(size_t)(st + k) * TLEN + u];
    float mt = (u >= st && u < st + 29) ? MtC[t * 29 + (u - st)] : 0.0f;
    V[id] = acc;
    U[id] = mt - acc;
}

// A = U + V@U, output bf16 (RNE); 16x16 LDS-tiled fp32 matmul (480^3, tiny)
__global__ void k_A(const float* __restrict__ U, const float* __restrict__ V,
                    u16* __restrict__ Abf) {
    __shared__ float Vs[16][17];
    __shared__ float Us[16][17];
    int tx = threadIdx.x, ty = threadIdx.y;
    int u = blockIdx.x * 16 + tx;
    int t = blockIdx.y * 16 + ty;
    float acc = 0.0f;
    for (int kt = 0; kt < 30; ++kt) {
        Vs[ty][tx] = V[(size_t)t * TLEN + kt * 16 + tx];
        Us[ty][tx] = U[(size_t)(kt * 16 + ty) * TLEN + u];
        __syncthreads();
        #pragma unroll
        for (int e = 0; e < 16; ++e) acc += Vs[ty][e] * Us[e][tx];
        __syncthreads();
    }
    Abf[(size_t)t * TLEN + u] = f2bf(U[(size_t)t * TLEN + u] + acc);
}

// Fused transpose+GEMM: trend = A @ x_b^T per batch; out1 = trend, out0 = x - trend.
//
// v3 (full-K staged): grid (b, 5 t-tiles of 96, 4 c-quarters of 64).  One block stages
// ALL of x[b, 0:480, cq*64 +: 64] -> LDS bf16 [c][k], row stride 488 u16 (16B-aligned;
// wave ds_read_b128 is bank-conflict-free by construction: span position (5*c + 4s +
// quad) mod 8 is uniform).  Staging is a single barrier-free burst (30 float4 loads
// per thread, reg double-buffered) -> deep MLP instead of 15 dependent round trips.
// Then ONE barrier, then a barrier-free software-pipelined MFMA loop (a/b fragments
// prefetched one k-step ahead), then an LDS-transposed epilogue: acc -> fp32 [96][68]
// in LDS (aliasing Xs), barrier, and streamed stores where EACH instruction writes
// 4 rows x 256B contiguous = 8 complete 128B lines (tests the nt write-amplification
// theory).  3 barriers total per block (was 15).  blockIdx.x = b keeps XCD affinity.
__global__ __launch_bounds__(256, 2)
void k_gemm(const u16* __restrict__ A, const float* __restrict__ x,
            float* __restrict__ out0, float* __restrict__ out1) {
    __shared__ u16 Xs[64 * 488];     // 62,464 B
    int b = blockIdx.x;
    int t0 = blockIdx.y * 96;
    int cz = blockIdx.z * 64;
    int tid = threadIdx.x;
    int wave = tid >> 6, lane = tid & 63;
    int lane15 = lane & 15, quad = lane >> 4;
    int wm = wave & 1, wn = wave >> 1;   // wave tile: 32c x 48t

    // ---- staging: x[b, 0:480, cz:cz+64] -> LDS bf16 [c][488] ----
    int wq  = tid & 15;      // c-quad (4 c's)
    int kkq = tid >> 4;      // k-quad (4 k's); pass covers 64 k
    const float* xp0 = x + (size_t)b * TLEN * NC + (size_t)(kkq * 4) * NC + cz + wq * 4;
    u32* l32 = (u32*)Xs;
    int lbase = (wq * 4) * 244 + kkq * 2;     // u32 offset; +cc*244 per channel, +p*32 per pass

    float4 ra[4], rb[4];
    {
        #pragma unroll
        for (int q = 0; q < 4; ++q) ra[q] = *(const float4*)(xp0 + q * NC);
    }
    #pragma unroll
    for (int p = 0; p < 8; ++p) {
        float4* cur = (p & 1) ? rb : ra;
        float4* nxt = (p & 1) ? ra : rb;
        if (p < 7) {   // issue next pass's loads before consuming cur
            if (p + 1 < 7 || kkq < 8) {
                const float* xp = xp0 + (size_t)(p + 1) * 64 * NC;
                #pragma unroll
                for (int q = 0; q < 4; ++q) nxt[q] = *(const float4*)(xp + q * NC);
            }
        }
        if (p < 7 || kkq < 8) {
            const float* fl = (const float*)cur;   // [r*4 + cc], compile-time indexed
            int o = lbase + p * 32;
            #pragma unroll
            for (int cc = 0; cc < 4; ++cc) {
                uint2 w;
                w.x = pack2bf(fl[0 * 4 + cc], fl[1 * 4 + cc]);
                w.y = pack2bf(fl[2 * 4 + cc], fl[3 * 4 + cc]);
                *(uint2*)(l32 + o + cc * 244) = w;
            }
        }
    }
    __syncthreads();   // barrier #1: LDS x-tile complete

    // ---- compute: 15 k-steps, software-pipelined, no barriers ----
    const u16* bp0 = A + (size_t)(t0 + wn * 48 + lane15) * TLEN + quad * 8;
    int arow = (wm * 32 + lane15) * 488 + quad * 8;    // u16 index into Xs

    f32x4 acc[2][3] = {};
    bf16x8 bcur[3], bnxt[3], acur[2], anxt[2];
    #pragma unroll
    for (int j = 0; j < 3; ++j) bcur[j] = *(const bf16x8*)(bp0 + (size_t)j * 16 * TLEN);
    acur[0] = *(const bf16x8*)&Xs[arow];
    acur[1] = *(const bf16x8*)&Xs[arow + 16 * 488];

    #pragma unroll
    for (int s = 0; s < 15; ++s) {
        bf16x8* bc = (s & 1) ? bnxt : bcur;
        bf16x8* bn = (s & 1) ? bcur : bnxt;
        bf16x8* ac = (s & 1) ? anxt : acur;
        bf16x8* an = (s & 1) ? acur : anxt;
        if (s < 14) {
            int k = (s + 1) * 32;
            #pragma unroll
            for (int j = 0; j < 3; ++j)
                bn[j] = *(const bf16x8*)(bp0 + (size_t)j * 16 * TLEN + k);
            an[0] = *(const bf16x8*)&Xs[arow + k];
            an[1] = *(const bf16x8*)&Xs[arow + 16 * 488 + k];
        }
        #pragma unroll
        for (int j = 0; j < 3; ++j) {
            acc[0][j] = __builtin_amdgcn_mfma_f32_16x16x32_bf16(ac[0], bc[j], acc[0][j], 0, 0, 0);
            acc[1][j] = __builtin_amdgcn_mfma_f32_16x16x32_bf16(ac[1], bc[j], acc[1][j], 0, 0, 0);
        }
    }

    __syncthreads();   // barrier #2: everyone done reading Xs; safe to alias

    // ---- epilogue: acc -> LDS fp32 [96][68] (x2 tensors), then line-complete stores ----
    float* T = (float*)Xs;          // trend  [96][68] = 26,112 B
    float* R = T + 96 * 68;         // resid  [96][68]; total 52,224 B <= 62,464
    #pragma unroll
    for (int j = 0; j < 3; ++j) {
        int tl = wn * 48 + j * 16 + lane15;
        #pragma unroll
        for (int i = 0; i < 2; ++i) {
            int clb = wm * 32 + i * 16 + quad * 4;
            f32x4 tv = acc[i][j];
            size_t gb = ((size_t)b * TLEN + t0 + tl) * NC + cz + clb;
            f32x4 xv = *(const f32x4*)(x + gb);
            *(f32x4*)&T[tl * 68 + clb] = tv;
            *(f32x4*)&R[tl * 68 + clb] = xv - tv;
        }
    }
    __syncthreads();   // barrier #3

    #pragma unroll
    for (int v = 0; v < 6; ++v) {
        int id = v * 256 + tid;
        int tl = id >> 4, c4 = (id & 15) * 4;
        size_t gb = ((size_t)b * TLEN + t0 + tl) * NC + cz + c4;
        f32x4 tv = *(const f32x4*)&T[tl * 68 + c4];
        f32x4 rv = *(const f32x4*)&R[tl * 68 + c4];
        __builtin_nontemporal_store(tv, (f32x4*)(out1 + gb));
        __builtin_nontemporal_store(rv, (f32x4*)(out0 + gb));
    }
}

extern "C" void kernel_launch(void* const* d_in, const int* in_sizes, int n_in,
                              void* d_out, int out_size, void* d_ws, size_t ws_size,
                              hipStream_t stream) {
    const float* x = (const float*)d_in[0];
    float* out0 = (float*)d_out;                           // seasonal + resid = x - trend
    float* out1 = (float*)d_out + (size_t)NB * TLEN * NC;  // trend

    char* ws = (char*)d_ws;
    size_t oMs  = 0;                       // 34*32*4 = 4352
    size_t oW3  = oMs + 4352;              // 128
    size_t oLpC = oW3 + 128;               // 480*17*4 = 32640
    size_t oMtC = oLpC + 32640;            // 480*29*4 = 55680
    size_t oS   = oMtC + 55680;            // 921600
    size_t oU   = oS + 921600;
    size_t oV   = oU + 921600;
    size_t oA   = oV + 921600;             // bf16 460800

    float* Ms   = (float*)(ws + oMs);
    float* w3   = (float*)(ws + oW3);
    float* MlpC = (float*)(ws + oLpC);
    float* MtC  = (float*)(ws + oMtC);
    float* S    = (float*)(ws + oS);
    float* U    = (float*)(ws + oU);
    float* V    = (float*)(ws + oV);
    u16*   Abf  = (u16*)(ws + oA);

    k_loess<<<5, 256, 0, stream>>>(Ms, w3, MlpC, MtC);
    k_S<<<900, 256, 0, stream>>>(Ms, w3, MlpC, S);
    k_VU<<<900, 256, 0, stream>>>(MtC, S, U, V);
    k_A<<<dim3(30, 30), dim3(16, 16), 0, stream>>>(U, V, Abf);
    k_gemm<<<dim3(NB, 5, 4), 256, 0, stream>>>(Abf, x, out0, out1);
}